// Round 1
// baseline (204.206 us; speedup 1.0000x reference)
//
#include <hip/hip_runtime.h>
#include <math.h>

// Fused autoencoder fwd + forward-mode Jacobians + analytic Jacobians.
// One thread per sample. Weights (708 floats) staged in LDS (broadcast reads).
//
// MLP: Linear(2,16) -> softplus -> Linear(16,16) -> softplus -> Linear(16,2)
// J = W3 . diag(sig(z2)) . W2 . diag(sig(z1)) . W1   (2x2 per sample)

__device__ __forceinline__ void mlp_jac(const float* __restrict__ s,
                                        float x0, float x1,
                                        float& o0, float& o1,
                                        float& J00, float& J01,
                                        float& J10, float& J11)
{
    // layout within s: w1[32] b1[16] w2[256] b2[16] w3[32] b3[2]
    const float* w1 = s;
    const float* b1 = s + 32;
    const float* w2 = s + 48;
    const float* b2 = s + 304;
    const float* w3 = s + 320;
    const float* b3 = s + 352;

    float h1[16], ta[16], tb[16];
#pragma unroll
    for (int j = 0; j < 16; ++j) {
        float wa = w1[2 * j], wb = w1[2 * j + 1];
        float z = fmaf(wa, x0, fmaf(wb, x1, b1[j]));
        float e = __expf(-fabsf(z));          // exp(-|z|) shared by softplus & sigmoid
        float inv = 1.0f / (1.0f + e);
        float sg = (z >= 0.0f) ? inv : e * inv;   // sigmoid(z)
        h1[j] = fmaxf(z, 0.0f) + __logf(1.0f + e); // stable softplus
        ta[j] = sg * wa;                       // diag(sg) * W1 column 0
        tb[j] = sg * wb;                       // column 1
    }

    o0 = b3[0]; o1 = b3[1];
    J00 = 0.0f; J01 = 0.0f; J10 = 0.0f; J11 = 0.0f;
#pragma unroll
    for (int i = 0; i < 16; ++i) {
        float z = b2[i], ua = 0.0f, ub = 0.0f;
        const float* w2row = w2 + 16 * i;
#pragma unroll
        for (int j = 0; j < 16; ++j) {
            float w = w2row[j];
            z  = fmaf(w, h1[j], z);
            ua = fmaf(w, ta[j], ua);
            ub = fmaf(w, tb[j], ub);
        }
        float e = __expf(-fabsf(z));
        float inv = 1.0f / (1.0f + e);
        float sg = (z >= 0.0f) ? inv : e * inv;
        float sp = fmaxf(z, 0.0f) + __logf(1.0f + e);
        ua *= sg; ub *= sg;
        float wo0 = w3[i], wo1 = w3[16 + i];
        o0  = fmaf(wo0, sp, o0);
        o1  = fmaf(wo1, sp, o1);
        J00 = fmaf(wo0, ua, J00);
        J01 = fmaf(wo0, ub, J01);
        J10 = fmaf(wo1, ua, J10);
        J11 = fmaf(wo1, ub, J11);
    }
}

__global__ __launch_bounds__(256) void ae_fused_kernel(
    const float* __restrict__ q,
    const float* __restrict__ ew1, const float* __restrict__ eb1,
    const float* __restrict__ ew2, const float* __restrict__ eb2,
    const float* __restrict__ ew3, const float* __restrict__ eb3,
    const float* __restrict__ dw1, const float* __restrict__ db1,
    const float* __restrict__ dw2, const float* __restrict__ db2,
    const float* __restrict__ dw3, const float* __restrict__ db3,
    float* __restrict__ out, int n)
{
    __shared__ float s[708];
    const int t = threadIdx.x;  // blockDim.x == 256

    // Stage all weights into LDS. enc block at 0, dec block at 354.
    if (t < 32) s[0   + t] = ew1[t];
    if (t < 16) s[32  + t] = eb1[t];
    s[48 + t] = ew2[t];
    if (t < 16) s[304 + t] = eb2[t];
    if (t < 32) s[320 + t] = ew3[t];
    if (t < 2)  s[352 + t] = eb3[t];
    if (t < 32) s[354 + t] = dw1[t];
    if (t < 16) s[386 + t] = db1[t];
    s[402 + t] = dw2[t];
    if (t < 16) s[658 + t] = db2[t];
    if (t < 32) s[674 + t] = dw3[t];
    if (t < 2)  s[706 + t] = db3[t];
    __syncthreads();

    const int i = blockIdx.x * 256 + t;
    if (i >= n) return;

    const float2 qv = ((const float2*)q)[i];
    const float x = qv.x, y = qv.y;

    // encoder + its jacobian
    float th0, th1, eJ00, eJ01, eJ10, eJ11;
    mlp_jac(s, x, y, th0, th1, eJ00, eJ01, eJ10, eJ11);

    // decoder (at theta) + its jacobian
    float qh0, qh1, dJ00, dJ01, dJ10, dJ11;
    mlp_jac(s + 354, th0, th1, qh0, qh1, dJ00, dJ01, dJ10, dJ11);

    // analytic jacobians: theta0 = atan2(y,x), theta1 = sqrt(x^2+y^2+eps)
    const float r2   = fmaf(x, x, y * y);
    const float inv  = 1.0f / r2;
    const float rinv = rsqrtf(r2 + 1e-8f);

    const size_t nn = (size_t)n;
    ((float2*)(out))[i]            = make_float2(th0, th1);
    ((float4*)(out + 2 * nn))[i]   = make_float4(eJ00, eJ01, eJ10, eJ11);
    ((float2*)(out + 6 * nn))[i]   = make_float2(qh0, qh1);
    ((float4*)(out + 8 * nn))[i]   = make_float4(dJ00, dJ01, dJ10, dJ11);
    ((float4*)(out + 12 * nn))[i]  = make_float4(-y * inv, x * inv, x * rinv, y * rinv);
}

extern "C" void kernel_launch(void* const* d_in, const int* in_sizes, int n_in,
                              void* d_out, int out_size, void* d_ws, size_t ws_size,
                              hipStream_t stream)
{
    const float* q   = (const float*)d_in[0];
    const float* ew1 = (const float*)d_in[1];
    const float* eb1 = (const float*)d_in[2];
    const float* ew2 = (const float*)d_in[3];
    const float* eb2 = (const float*)d_in[4];
    const float* ew3 = (const float*)d_in[5];
    const float* eb3 = (const float*)d_in[6];
    const float* dw1 = (const float*)d_in[7];
    const float* db1 = (const float*)d_in[8];
    const float* dw2 = (const float*)d_in[9];
    const float* db2 = (const float*)d_in[10];
    const float* dw3 = (const float*)d_in[11];
    const float* db3 = (const float*)d_in[12];

    const int n = in_sizes[0] / 2;
    const int grid = (n + 255) / 256;
    ae_fused_kernel<<<grid, 256, 0, stream>>>(
        q, ew1, eb1, ew2, eb2, ew3, eb3,
        dw1, db1, dw2, db2, dw3, db3,
        (float*)d_out, n);
}

// Round 2
// 160.776 us; speedup vs baseline: 1.2701x; 1.2701x over previous
//
#include <hip/hip_runtime.h>
#include <math.h>

// Fused autoencoder fwd + forward-mode Jacobians + analytic Jacobians.
// One thread per sample. Weights read as wave-uniform scalar loads (s_load
// through the constant cache) -- no LDS, no per-lane weight VGPRs.
// Jacobian accumulation packed into v_pk_fma_f32 via <2 x float>.
//
// MLP: Linear(2,16) -> softplus -> Linear(16,16) -> softplus -> Linear(16,2)
// J = W3 . diag(sig(z2)) . W2 . diag(sig(z1)) . W1   (2x2 per sample)

typedef float v2f __attribute__((ext_vector_type(2)));

__device__ __forceinline__ float fast_rcp(float x) {
    return __builtin_amdgcn_rcpf(x);   // raw v_rcp_f32 (~1 ulp) -- threshold is bf16-floor
}

__device__ __forceinline__ v2f splat(float x) { v2f r; r.x = x; r.y = x; return r; }

__device__ __forceinline__ void mlp_jac(
    const float* __restrict__ w1, const float* __restrict__ b1,
    const float* __restrict__ w2, const float* __restrict__ b2,
    const float* __restrict__ w3, const float* __restrict__ b3,
    float x0, float x1,
    float& o0, float& o1, v2f& J0, v2f& J1)
{
    float h1[16];
    v2f   tab[16];   // diag(sigmoid(z1)) * W1  (rows as float2)
#pragma unroll
    for (int j = 0; j < 16; ++j) {
        float wa = w1[2 * j], wb = w1[2 * j + 1];
        float z  = fmaf(wa, x0, fmaf(wb, x1, b1[j]));
        float e  = __expf(-fabsf(z));            // exp(-|z|) shared by softplus & sigmoid
        float iv = fast_rcp(1.0f + e);
        float sg = (z >= 0.0f) ? iv : e * iv;    // sigmoid(z)
        h1[j] = fmaxf(z, 0.0f) + __logf(1.0f + e); // stable softplus
        v2f w12; w12.x = wa; w12.y = wb;
        tab[j] = splat(sg) * w12;
    }

    v2f o; o.x = b3[0]; o.y = b3[1];
    J0 = splat(0.0f); J1 = splat(0.0f);
#pragma unroll
    for (int i = 0; i < 16; ++i) {
        float z   = b2[i];
        v2f   uab = splat(0.0f);
        const float* w2row = w2 + 16 * i;
#pragma unroll
        for (int j = 0; j < 16; ++j) {
            float w = w2row[j];
            z   = fmaf(w, h1[j], z);
            uab = __builtin_elementwise_fma(splat(w), tab[j], uab);
        }
        float e  = __expf(-fabsf(z));
        float iv = fast_rcp(1.0f + e);
        float sg = (z >= 0.0f) ? iv : e * iv;
        float sp = fmaxf(z, 0.0f) + __logf(1.0f + e);
        uab = splat(sg) * uab;
        float wo0 = w3[i], wo1 = w3[16 + i];
        v2f wo; wo.x = wo0; wo.y = wo1;
        o  = __builtin_elementwise_fma(wo, splat(sp), o);
        J0 = __builtin_elementwise_fma(splat(wo0), uab, J0);
        J1 = __builtin_elementwise_fma(splat(wo1), uab, J1);
    }
    o0 = o.x; o1 = o.y;
}

__global__ __launch_bounds__(256) void ae_fused_kernel(
    const float* __restrict__ q,
    const float* __restrict__ ew1, const float* __restrict__ eb1,
    const float* __restrict__ ew2, const float* __restrict__ eb2,
    const float* __restrict__ ew3, const float* __restrict__ eb3,
    const float* __restrict__ dw1, const float* __restrict__ db1,
    const float* __restrict__ dw2, const float* __restrict__ db2,
    const float* __restrict__ dw3, const float* __restrict__ db3,
    float* __restrict__ out, int n)
{
    const int i = blockIdx.x * 256 + threadIdx.x;
    if (i >= n) return;

    const float2 qv = ((const float2*)q)[i];
    const float x = qv.x, y = qv.y;

    // encoder + its jacobian
    float th0, th1; v2f eJ0, eJ1;
    mlp_jac(ew1, eb1, ew2, eb2, ew3, eb3, x, y, th0, th1, eJ0, eJ1);

    // decoder (at theta) + its jacobian
    float qh0, qh1; v2f dJ0, dJ1;
    mlp_jac(dw1, db1, dw2, db2, dw3, db3, th0, th1, qh0, qh1, dJ0, dJ1);

    // analytic jacobians: theta0 = atan2(y,x), theta1 = sqrt(x^2+y^2+eps)
    const float r2   = fmaf(x, x, y * y);
    const float iv   = fast_rcp(r2);
    const float rinv = __builtin_amdgcn_rsqf(r2 + 1e-8f);

    const size_t nn = (size_t)n;
    ((float2*)(out))[i]           = make_float2(th0, th1);
    ((float4*)(out + 2 * nn))[i]  = make_float4(eJ0.x, eJ0.y, eJ1.x, eJ1.y);
    ((float2*)(out + 6 * nn))[i]  = make_float2(qh0, qh1);
    ((float4*)(out + 8 * nn))[i]  = make_float4(dJ0.x, dJ0.y, dJ1.x, dJ1.y);
    ((float4*)(out + 12 * nn))[i] = make_float4(-y * iv, x * iv, x * rinv, y * rinv);
}

extern "C" void kernel_launch(void* const* d_in, const int* in_sizes, int n_in,
                              void* d_out, int out_size, void* d_ws, size_t ws_size,
                              hipStream_t stream)
{
    const float* q   = (const float*)d_in[0];
    const float* ew1 = (const float*)d_in[1];
    const float* eb1 = (const float*)d_in[2];
    const float* ew2 = (const float*)d_in[3];
    const float* eb2 = (const float*)d_in[4];
    const float* ew3 = (const float*)d_in[5];
    const float* eb3 = (const float*)d_in[6];
    const float* dw1 = (const float*)d_in[7];
    const float* db1 = (const float*)d_in[8];
    const float* dw2 = (const float*)d_in[9];
    const float* db2 = (const float*)d_in[10];
    const float* dw3 = (const float*)d_in[11];
    const float* db3 = (const float*)d_in[12];

    const int n = in_sizes[0] / 2;
    const int grid = (n + 255) / 256;
    ae_fused_kernel<<<grid, 256, 0, stream>>>(
        q, ew1, eb1, ew2, eb2, ew3, eb3,
        dw1, db1, dw2, db2, dw3, db3,
        (float*)d_out, n);
}